// Round 16
// baseline (78.929 us; speedup 1.0000x reference)
//
#include <hip/hip_runtime.h>
#include <math.h>

// 23-qubit statevector: 23 U3 gates (qubit q acts on global bit 22-q), then a
// CNOT cascade == Gray permutation out[y] = mid[y ^ (y>>1)].
// R16:
//   pass_high: gates {0,1}u{14..22} (11 gates) — R12/R15 VERBATIM fp32
//              (2-tile fused, grid 256, sigma=pxor9(row) stores). ~32 µs.
//   pass_low : gates {2..13} (12 gates) — R15's clean-slot schedule and
//              telescoped coalesced Gray-store (HW-verified), with registers
//              re-expressed as f2 (float2 ext-vector) pairs so every gate is
//              a packed 2-wide op (R7 evidence: f2 pass_low ≈38 µs vs 44 fp32).
//     x_pre = (w<<8)|(j<<6)|l (f4); f2 k=2j+(amp bit1), comp = amp bit0.
//     Pre : q20(dpp1,l0) q19(dpp2,l1) q16(x16,l4) q15(x32,l5) q14(reg0=f2bit1)
//           q13(reg1=f2bit2)
//     RT read slot = l23 | l01<<2 | w<<4 | l45<<8 | j<<10
//     Post: q18(dpp1,l0) q17(dpp2,l1) q12(x16,l4) q11(x32,l5) q10(reg0) q9(reg1)
//     Store t: n=l2|l3<<1|l0<<2|l1<<3; pn=pxor4(n); pw=pxor4(w); W=pw&1;
//       Pj=j0^j1; S8=l4^l5^Pj; K=W^S8;
//       t=(pn^K*0xF)|((pw^S8*0xF)<<4)|(S8<<8)|((l5^Pj)<<9)|(Pj<<10)|(j1<<11)
//       addr = t ^ 0xFFF*(c&1); comps (x,y,w,z) reversed iff (t^c)&1.

#define NTOT (1u << 23)

typedef unsigned int u2 __attribute__((ext_vector_type(2)));
typedef float f2 __attribute__((ext_vector_type(2)));

struct G8 { float r00,i00,r01,i01,r10,i10,r11,i11; };

__device__ __forceinline__ f2 sp(float s) { return (f2){s, s}; }

__device__ __forceinline__ G8 u3_lane(const float* __restrict__ p, int q) {
    float a = p[3*q+0], b = p[3*q+1], c = p[3*q+2];
    float cb = cosf(b*0.5f), sb = sinf(b*0.5f);
    float ph = (a+c)*0.5f, m = (a-c)*0.5f;
    float cp = cosf(ph), sp_ = sinf(ph);
    float cm = cosf(m),  sm = sinf(m);
    G8 g;
    g.r00 =  cb*cp; g.i00 = -cb*sp_;
    g.r01 = -sb*cm; g.i01 =  sb*sm;
    g.r10 =  sb*cm; g.i10 =  sb*sm;
    g.r11 =  cb*cp; g.i11 =  cb*sp_;
    return g;
}

__device__ __forceinline__ float rdl(float v, int q) {
    return __uint_as_float(__builtin_amdgcn_readlane(__float_as_uint(v), q));
}
__device__ __forceinline__ G8 gread(const G8& m, int q) {
    G8 g;
    g.r00=rdl(m.r00,q); g.i00=rdl(m.i00,q);
    g.r01=rdl(m.r01,q); g.i01=rdl(m.i01,q);
    g.r10=rdl(m.r10,q); g.i10=rdl(m.i10,q);
    g.r11=rdl(m.r11,q); g.i11=rdl(m.i11,q);
    return g;
}

// ---- fp32 butterfly helpers (pass_high) ----
__device__ __forceinline__ void bfs(float& x0r, float& x0i, float& x1r, float& x1i, const G8& g) {
    float y0r = g.r00*x0r - g.i00*x0i + g.r01*x1r - g.i01*x1i;
    float y0i = g.r00*x0i + g.i00*x0r + g.r01*x1i + g.i01*x1r;
    float y1r = g.r10*x0r - g.i10*x0i + g.r11*x1r - g.i11*x1i;
    float y1i = g.r10*x0i + g.i10*x0r + g.r11*x1i + g.i11*x1r;
    x0r=y0r; x0i=y0i; x1r=y1r; x1i=y1i;
}
__device__ __forceinline__ void bf4v(float4& ar, float4& ai, float4& br, float4& bi, const G8& g) {
    bfs(ar.x, ai.x, br.x, bi.x, g);
    bfs(ar.y, ai.y, br.y, bi.y, g);
    bfs(ar.z, ai.z, br.z, bi.z, g);
    bfs(ar.w, ai.w, br.w, bi.w, g);
}
__device__ __forceinline__ void bfc0(float4& r, float4& i, const G8& g) {
    bfs(r.x, i.x, r.y, i.y, g); bfs(r.z, i.z, r.w, i.w, g);
}
__device__ __forceinline__ void bfc1(float4& r, float4& i, const G8& g) {
    bfs(r.x, i.x, r.z, i.z, g); bfs(r.y, i.y, r.w, i.w, g);
}
__device__ __forceinline__ void reg_gate0(float4 (&xr)[4], float4 (&xi)[4], const G8& g) {
    bf4v(xr[0],xi[0],xr[1],xi[1],g); bf4v(xr[2],xi[2],xr[3],xi[3],g);
}
__device__ __forceinline__ void reg_gate1(float4 (&xr)[4], float4 (&xi)[4], const G8& g) {
    bf4v(xr[0],xi[0],xr[2],xi[2],g); bf4v(xr[1],xi[1],xr[3],xi[3],g);
}

// ---- f2 packed butterfly helpers (pass_low) ----
__device__ __forceinline__ void bfs2(f2& x0r, f2& x0i, f2& x1r, f2& x1i, const G8& g) {
    f2 y0r = sp(g.r00)*x0r - sp(g.i00)*x0i + sp(g.r01)*x1r - sp(g.i01)*x1i;
    f2 y0i = sp(g.r00)*x0i + sp(g.i00)*x0r + sp(g.r01)*x1i + sp(g.i01)*x1r;
    f2 y1r = sp(g.r10)*x0r - sp(g.i10)*x0i + sp(g.r11)*x1r - sp(g.i11)*x1i;
    f2 y1i = sp(g.r10)*x0i + sp(g.i10)*x0r + sp(g.r11)*x1i + sp(g.i11)*x1r;
    x0r=y0r; x0i=y0i; x1r=y1r; x1i=y1i;
}
// f4-index bit0 = f2-index bit1; f4-index bit1 = f2-index bit2
__device__ __forceinline__ void reg2_gate0(f2 (&xr)[8], f2 (&xi)[8], const G8& g) {
    bfs2(xr[0],xi[0],xr[2],xi[2],g); bfs2(xr[1],xi[1],xr[3],xi[3],g);
    bfs2(xr[4],xi[4],xr[6],xi[6],g); bfs2(xr[5],xi[5],xr[7],xi[7],g);
}
__device__ __forceinline__ void reg2_gate1(f2 (&xr)[8], f2 (&xi)[8], const G8& g) {
    bfs2(xr[0],xi[0],xr[4],xi[4],g); bfs2(xr[1],xi[1],xr[5],xi[5],g);
    bfs2(xr[2],xi[2],xr[6],xi[6],g); bfs2(xr[3],xi[3],xr[7],xi[7],g);
}

// ---- lane-partner fetchers (per 32-bit component) ----
__device__ __forceinline__ float p_dpp1(float x) {
    return __uint_as_float((unsigned)__builtin_amdgcn_update_dpp(
        0, (int)__float_as_uint(x), 0xB1, 0xF, 0xF, true));   // quad_perm [1,0,3,2]
}
__device__ __forceinline__ float p_dpp2(float x) {
    return __uint_as_float((unsigned)__builtin_amdgcn_update_dpp(
        0, (int)__float_as_uint(x), 0x4E, 0xF, 0xF, true));   // quad_perm [2,3,0,1]
}
__device__ __forceinline__ float p_x16(float x, int hi) {
#if __has_builtin(__builtin_amdgcn_permlane16_swap)
    u2 r = __builtin_amdgcn_permlane16_swap(__float_as_uint(x), __float_as_uint(x), false, false);
    return __uint_as_float(hi ? r[0] : r[1]);
#else
    (void)hi;
    return __uint_as_float((unsigned)__builtin_amdgcn_ds_swizzle(
        (int)__float_as_uint(x), 0x401F));                    // BitMode xor 16
#endif
}
__device__ __forceinline__ float p_x32(float x, int hi) {
#if __has_builtin(__builtin_amdgcn_permlane32_swap)
    u2 r = __builtin_amdgcn_permlane32_swap(__float_as_uint(x), __float_as_uint(x), false, false);
    return __uint_as_float(hi ? r[0] : r[1]);
#else
    (void)hi;
    return __shfl_xor(x, 32, 64);
#endif
}

// fp32 lane-bit gate (pass_high), per-f4 fused fetch+combine
#define MAKE_PGATE(NAME, FETCH)                                                     \
__device__ __forceinline__ void NAME(float4 (&xr)[4], float4 (&xi)[4],              \
                                     const G8& g, int bit, int hi) {                \
    float cor = bit ? g.r11 : g.r00, coi = bit ? g.i11 : g.i00;                     \
    float cpr = bit ? g.r10 : g.r01, cpi = bit ? g.i10 : g.i01;                     \
    (void)hi;                                                                       \
    _Pragma("unroll")                                                               \
    for (int i = 0; i < 4; ++i) {                                                   \
        float4 pr, pi, nr, ni;                                                      \
        pr.x = FETCH(xr[i].x); pr.y = FETCH(xr[i].y);                               \
        pr.z = FETCH(xr[i].z); pr.w = FETCH(xr[i].w);                               \
        pi.x = FETCH(xi[i].x); pi.y = FETCH(xi[i].y);                               \
        pi.z = FETCH(xi[i].z); pi.w = FETCH(xi[i].w);                               \
        nr.x = cor*xr[i].x - coi*xi[i].x + cpr*pr.x - cpi*pi.x;                     \
        ni.x = cor*xi[i].x + coi*xr[i].x + cpr*pi.x + cpi*pr.x;                     \
        nr.y = cor*xr[i].y - coi*xi[i].y + cpr*pr.y - cpi*pi.y;                     \
        ni.y = cor*xi[i].y + coi*xr[i].y + cpr*pi.y + cpi*pr.y;                     \
        nr.z = cor*xr[i].z - coi*xi[i].z + cpr*pr.z - cpi*pi.z;                     \
        ni.z = cor*xi[i].z + coi*xr[i].z + cpr*pi.z + cpi*pr.z;                     \
        nr.w = cor*xr[i].w - coi*xi[i].w + cpr*pr.w - cpi*pi.w;                     \
        ni.w = cor*xi[i].w + coi*xr[i].w + cpr*pi.w + cpi*pr.w;                     \
        xr[i] = nr; xi[i] = ni;                                                     \
    }                                                                               \
}
// f2 packed lane-bit gate (pass_low), per-f2 fused fetch+combine
#define MAKE_PGATE2(NAME, FETCH)                                                    \
__device__ __forceinline__ void NAME(f2 (&xr)[8], f2 (&xi)[8],                      \
                                     const G8& g, int bit, int hi) {                \
    float cor = bit ? g.r11 : g.r00, coi = bit ? g.i11 : g.i00;                     \
    float cpr = bit ? g.r10 : g.r01, cpi = bit ? g.i10 : g.i01;                     \
    (void)hi;                                                                       \
    _Pragma("unroll")                                                               \
    for (int i = 0; i < 8; ++i) {                                                   \
        f2 pr, pi;                                                                  \
        pr.x = FETCH(xr[i].x); pr.y = FETCH(xr[i].y);                               \
        pi.x = FETCH(xi[i].x); pi.y = FETCH(xi[i].y);                               \
        f2 nr = sp(cor)*xr[i] - sp(coi)*xi[i] + sp(cpr)*pr - sp(cpi)*pi;            \
        f2 ni = sp(cor)*xi[i] + sp(coi)*xr[i] + sp(cpr)*pi + sp(cpi)*pr;            \
        xr[i] = nr; xi[i] = ni;                                                     \
    }                                                                               \
}
#define F_DPP1(v) p_dpp1(v)
#define F_DPP2(v) p_dpp2(v)
#define F_X16(v)  p_x16(v, hi)
#define F_X32(v)  p_x32(v, hi)
MAKE_PGATE(gate_dpp1, F_DPP1)
MAKE_PGATE(gate_x16,  F_X16)
MAKE_PGATE(gate_x32,  F_X32)
MAKE_PGATE2(gate2_dpp1, F_DPP1)
MAKE_PGATE2(gate2_dpp2, F_DPP2)
MAKE_PGATE2(gate2_x16,  F_X16)
MAKE_PGATE2(gate2_x32,  F_X32)

__device__ __forceinline__ int pxor9(int x)  { x^=x>>1; x^=x>>2; x^=x>>4; x^=x>>8; return x & 0x1FF; }
__device__ __forceinline__ int pxor4(int x)  { x^=x>>1; x^=x>>2; return x & 0xF; }

// ================= pass_high (R12/R15 verbatim: 11 gates {0,1}u{14..22}) =====
__device__ __forceinline__ void highA(float4 (&xr)[4], float4 (&xi)[4],
                                      const G8& my, int h16, int h32) {
    { G8 g = gread(my,22);
#pragma unroll
      for (int j = 0; j < 4; ++j) bfc0(xr[j], xi[j], g); }
    { G8 g = gread(my,21);
#pragma unroll
      for (int j = 0; j < 4; ++j) bfc1(xr[j], xi[j], g); }
    { G8 g = gread(my,5); reg_gate0(xr, xi, g); }
    { G8 g = gread(my,4); reg_gate1(xr, xi, g); }
    { G8 g = gread(my,7); gate_x16(xr, xi, g, h16, h16); }
    { G8 g = gread(my,6); gate_x32(xr, xi, g, h32, h32); }
}
__device__ __forceinline__ void wr_high(char* L, int l, int w,
                                        const float4 (&xr)[4], const float4 (&xi)[4]) {
    const int wslot = ((w << 8) | l) << 4;
#pragma unroll
    for (int j = 0; j < 4; ++j) {
        int a = wslot | (j << 10);
        *(float4*)(L + a) = xr[j];
        *(float4*)(L + a + 65536) = xi[j];
    }
}
__device__ __forceinline__ void rd_high(const char* L, int l, int w,
                                        float4 (&xr)[4], float4 (&xi)[4]) {
    const int sbase = (((l >> 1) & 7) | ((w & 3) << 4) | (((w >> 2) & 3) << 6)
                    | (((l >> 4) & 3) << 9) | ((l & 1) << 11)) << 4;
    constexpr int OFF[4] = {0, 8 << 4, 256 << 4, 264 << 4};
#pragma unroll
    for (int j = 0; j < 4; ++j) {
        int a = sbase | OFF[j];
        xr[j] = *(const float4*)(L + a);
        xi[j] = *(const float4*)(L + a + 65536);
    }
}
__device__ __forceinline__ void highB_store(float4 (&xr)[4], float4 (&xi)[4],
        const G8& my, int l, int w, int blk, int b1, int h16, int h32,
        float4* __restrict__ OR4, float4* __restrict__ OI4) {
    { G8 g = gread(my,8); reg_gate0(xr, xi, g); }
    { G8 g = gread(my,3); reg_gate1(xr, xi, g); }
    { G8 g = gread(my,0); gate_dpp1(xr, xi, g, b1, 0); }
    { G8 g = gread(my,2); gate_x16(xr, xi, g, h16, h16); }
    { G8 g = gread(my,1); gate_x32(xr, xi, g, h32, h32); }
    const int row_base = ((w & 15) << 1) | (((l >> 4) & 3) << 6) | ((l & 1) << 8);
    const int sg = pxor9(row_base);
    const size_t ob = ((size_t)blk << 3) | (size_t)((l >> 1) & 7);
    constexpr int SJ[4] = {0, 0x01, 0x3F, 0x3E};
#pragma unroll
    for (int j = 0; j < 4; ++j) {
        size_t F = (((size_t)(sg ^ SJ[j])) << 12) | ob;
        OR4[F] = xr[j]; OI4[F] = xi[j];
    }
}

__global__ __launch_bounds__(1024, 4)
void pass_high(const float* __restrict__ in_re, const float* __restrict__ in_im,
               const float* __restrict__ param,
               float* __restrict__ out_re, float* __restrict__ out_im) {
    __shared__ __align__(16) char L[131072];
    const int tid = threadIdx.x;
    const int l = tid & 63, w = tid >> 6;
    const int blkA = blockIdx.x, blkB = blockIdx.x + 256;

    const float4* R4p = (const float4*)in_re;
    const float4* I4p = (const float4*)in_im;
    float4 ar[4], ai[4], br_[4], bi_[4];
    const int rb = (l >> 3) | (w << 5);
    const size_t gA = ((size_t)blkA << 3) | (size_t)(l & 7);
    const size_t gB = ((size_t)blkB << 3) | (size_t)(l & 7);
#pragma unroll
    for (int j = 0; j < 4; ++j) {
        size_t gi = (((size_t)(rb | (j << 3))) << 12) | gA;
        ar[j] = R4p[gi]; ai[j] = I4p[gi];
    }
#pragma unroll
    for (int j = 0; j < 4; ++j) {
        size_t gi = (((size_t)(rb | (j << 3))) << 12) | gB;
        br_[j] = R4p[gi]; bi_[j] = I4p[gi];
    }
    G8 my = u3_lane(param, l < 23 ? l : 22);   // trig overlaps loads
    const int b1  = l & 1;
    const int h16 = (l >> 4) & 1, h32 = (l >> 5) & 1;
    float4* OR4 = (float4*)out_re;
    float4* OI4 = (float4*)out_im;

    // Tile A
    highA(ar, ai, my, h16, h32);
    wr_high(L, l, w, ar, ai);                  // LDS virgin: no pre-sync
    __syncthreads();
    rd_high(L, l, w, ar, ai);
    highB_store(ar, ai, my, l, w, blkA, b1, h16, h32, OR4, OI4);  // stores async
    // Tile B epoch A overlaps tile A store drain
    highA(br_, bi_, my, h16, h32);
    __syncthreads();                           // all A RT-reads complete
    wr_high(L, l, w, br_, bi_);
    __syncthreads();
    rd_high(L, l, w, br_, bi_);
    highB_store(br_, bi_, my, l, w, blkB, b1, h16, h32, OR4, OI4);
}

// ================= pass_low: gates {2..13}, f2-packed, clean slots ==========
// All addressing identical to R15 (HW-verified); registers are f2 pairs.
__global__ __launch_bounds__(1024, 4)
void pass_low(float* __restrict__ sre, float* __restrict__ sim,
              const float* __restrict__ param) {
    __shared__ __align__(16) char L[131072];
    const int tid = threadIdx.x, c = blockIdx.x;
    const int l = tid & 63, w = tid >> 6;
    G8 my = u3_lane(param, l < 23 ? l : 22);
    f2 xr[8], xi[8];

    float4* R4p = (float4*)sre;
    float4* I4p = (float4*)sim;
    const size_t cb = ((size_t)c) << 12;
    const int sw0 = (w << 8) | l;
#pragma unroll
    for (int j = 0; j < 4; ++j) {
        size_t fi = cb | (size_t)(sw0 | (j << 6));
        float4 tr = R4p[fi], ti = I4p[fi];
        xr[2*j] = (f2){tr.x, tr.y}; xr[2*j+1] = (f2){tr.z, tr.w};
        xi[2*j] = (f2){ti.x, ti.y}; xi[2*j+1] = (f2){ti.z, ti.w};
    }
    const int b1 = l & 1, b2 = (l >> 1) & 1;
    const int h16 = (l >> 4) & 1, h32 = (l >> 5) & 1;

    // pre-RT gates: amp{2,3,6,7,8,9}
    { G8 g = gread(my,20); gate2_dpp1(xr, xi, g, b1, 0); }
    { G8 g = gread(my,19); gate2_dpp2(xr, xi, g, b2, 0); }
    { G8 g = gread(my,16); gate2_x16(xr, xi, g, h16, h16); }
    { G8 g = gread(my,15); gate2_x32(xr, xi, g, h32, h32); }
    { G8 g = gread(my,14); reg2_gate0(xr, xi, g); }
    { G8 g = gread(my,13); reg2_gate1(xr, xi, g); }

    // RT write (identity layout) — all global loads consumed above, so the
    // barrier also makes the in-place stores safe.
#pragma unroll
    for (int j = 0; j < 4; ++j) {
        int a = (sw0 | (j << 6)) << 4;
        *(float4*)(L + a) = make_float4(xr[2*j].x, xr[2*j].y, xr[2*j+1].x, xr[2*j+1].y);
        *(float4*)(L + a + 65536) = make_float4(xi[2*j].x, xi[2*j].y, xi[2*j+1].x, xi[2*j+1].y);
    }
    __syncthreads();
    // RT read: slot = l23 | l01<<2 | w<<4 | l45<<8 | j<<10
    const int sb = ((l >> 2) & 3) | ((l & 3) << 2) | ((w & 15) << 4)
                 | (((l >> 4) & 3) << 8);
#pragma unroll
    for (int j = 0; j < 4; ++j) {
        int a = (sb | (j << 10)) << 4;
        float4 tr = *(const float4*)(L + a);
        float4 ti = *(const float4*)(L + a + 65536);
        xr[2*j] = (f2){tr.x, tr.y}; xr[2*j+1] = (f2){tr.z, tr.w};
        xi[2*j] = (f2){ti.x, ti.y}; xi[2*j+1] = (f2){ti.z, ti.w};
    }

    // post-RT gates: amp{4,5,10,11,12,13}
    { G8 g = gread(my,18); gate2_dpp1(xr, xi, g, b1, 0); }
    { G8 g = gread(my,17); gate2_dpp2(xr, xi, g, b2, 0); }
    { G8 g = gread(my,12); gate2_x16(xr, xi, g, h16, h16); }
    { G8 g = gread(my,11); gate2_x32(xr, xi, g, h32, h32); }
    { G8 g = gread(my,10); reg2_gate0(xr, xi, g); }
    { G8 g = gread(my, 9); reg2_gate1(xr, xi, g); }

    // Gray-gather store, coalesced (256 B segments per 16-lane group)
    const int codd = c & 1;
    const int A12 = codd ? 0xFFF : 0;
    const int l45x = h16 ^ h32;
    const int n  = ((l >> 2) & 3) | ((l & 3) << 2);   // l2|l3<<1|l0<<2|l1<<3
    const int pn = pxor4(n);
    const int pw = pxor4(w);
    const int W  = pw & 1;
#pragma unroll
    for (int j = 0; j < 4; ++j) {
        int j0 = j & 1, j1 = (j >> 1) & 1;
        int Pj = j0 ^ j1;
        int S8 = l45x ^ Pj;
        int K  = W ^ S8;
        int t = (pn ^ (K ? 0xF : 0))
              | ((pw ^ (S8 ? 0xF : 0)) << 4)
              | (S8 << 8)
              | ((h32 ^ Pj) << 9)
              | (Pj << 10)
              | (j1 << 11);
        int of4 = t ^ A12;
        int b = (t ^ codd) & 1;
        // s = (x, y, w, z) of the logical f4 = (xr[2j].x, xr[2j].y, xr[2j+1].y, xr[2j+1].x)
        float s0r = xr[2*j].x, s1r = xr[2*j].y, s2r = xr[2*j+1].y, s3r = xr[2*j+1].x;
        float s0i = xi[2*j].x, s1i = xi[2*j].y, s2i = xi[2*j+1].y, s3i = xi[2*j+1].x;
        float o0r = b ? s3r : s0r, o1r = b ? s2r : s1r, o2r = b ? s1r : s2r, o3r = b ? s0r : s3r;
        float o0i = b ? s3i : s0i, o1i = b ? s2i : s1i, o2i = b ? s1i : s2i, o3i = b ? s0i : s3i;
        size_t oo = cb | (size_t)of4;
        R4p[oo] = make_float4(o0r, o1r, o2r, o3r);
        I4p[oo] = make_float4(o0i, o1i, o2i, o3i);
    }
}

extern "C" void kernel_launch(void* const* d_in, const int* in_sizes, int n_in,
                              void* d_out, int out_size, void* d_ws, size_t ws_size,
                              hipStream_t stream) {
    (void)in_sizes; (void)n_in; (void)d_ws; (void)ws_size; (void)out_size;
    const float* in_re = (const float*)d_in[0];
    const float* in_im = (const float*)d_in[1];
    const float* param = (const float*)d_in[2];
    float* out_re = (float*)d_out;
    float* out_im = (float*)d_out + NTOT;

    pass_high<<<256, 1024, 0, stream>>>(in_re, in_im, param, out_re, out_im);
    pass_low <<<512, 1024, 0, stream>>>(out_re, out_im, param);
}

// Round 17
// 76.040 us; speedup vs baseline: 1.0380x; 1.0380x over previous
//
#include <hip/hip_runtime.h>
#include <math.h>

// 23-qubit statevector: 23 U3 gates (qubit q acts on global bit 22-q), then a
// CNOT cascade == Gray permutation out[y] = mid[y ^ (y>>1)].
// R17 = R9 VERBATIM (best measured: 76.4 us).
// pass_high: gates {0,1}u{14..22}, chunk-level Gray-decode sigma=pxor9(row).
// pass_low : gates {2..13}, in-chunk Gray gather t = pxor14(x)^0x3FFF*(c&1).
// Both: grid 256, each block owns tiles (b, b+256), both tiles' global loads
// issued at kernel start, 3 barriers:
//   A.RTwrite(virgin) | sync | A.RTread | A.epochB+A.store+B.epochA | sync |
//   B.RTwrite | sync | B.RTread | B.epochB+B.store

#define NTOT (1u << 23)

typedef unsigned int u2 __attribute__((ext_vector_type(2)));

struct G8 { float r00,i00,r01,i01,r10,i10,r11,i11; };

__device__ __forceinline__ G8 u3_lane(const float* __restrict__ p, int q) {
    float a = p[3*q+0], b = p[3*q+1], c = p[3*q+2];
    float cb = cosf(b*0.5f), sb = sinf(b*0.5f);
    float ph = (a+c)*0.5f, m = (a-c)*0.5f;
    float cp = cosf(ph), sp = sinf(ph);
    float cm = cosf(m),  sm = sinf(m);
    G8 g;
    g.r00 =  cb*cp; g.i00 = -cb*sp;
    g.r01 = -sb*cm; g.i01 =  sb*sm;
    g.r10 =  sb*cm; g.i10 =  sb*sm;
    g.r11 =  cb*cp; g.i11 =  cb*sp;
    return g;
}

__device__ __forceinline__ float rdl(float v, int q) {
    return __uint_as_float(__builtin_amdgcn_readlane(__float_as_uint(v), q));
}
__device__ __forceinline__ G8 gread(const G8& m, int q) {
    G8 g;
    g.r00=rdl(m.r00,q); g.i00=rdl(m.i00,q);
    g.r01=rdl(m.r01,q); g.i01=rdl(m.i01,q);
    g.r10=rdl(m.r10,q); g.i10=rdl(m.i10,q);
    g.r11=rdl(m.r11,q); g.i11=rdl(m.i11,q);
    return g;
}

__device__ __forceinline__ void bfs(float& x0r, float& x0i, float& x1r, float& x1i, const G8& g) {
    float y0r = g.r00*x0r - g.i00*x0i + g.r01*x1r - g.i01*x1i;
    float y0i = g.r00*x0i + g.i00*x0r + g.r01*x1i + g.i01*x1r;
    float y1r = g.r10*x0r - g.i10*x0i + g.r11*x1r - g.i11*x1i;
    float y1i = g.r10*x0i + g.i10*x0r + g.r11*x1i + g.i11*x1r;
    x0r=y0r; x0i=y0i; x1r=y1r; x1i=y1i;
}
__device__ __forceinline__ void bf4v(float4& ar, float4& ai, float4& br, float4& bi, const G8& g) {
    bfs(ar.x, ai.x, br.x, bi.x, g);
    bfs(ar.y, ai.y, br.y, bi.y, g);
    bfs(ar.z, ai.z, br.z, bi.z, g);
    bfs(ar.w, ai.w, br.w, bi.w, g);
}
__device__ __forceinline__ void bfc0(float4& r, float4& i, const G8& g) {
    bfs(r.x, i.x, r.y, i.y, g); bfs(r.z, i.z, r.w, i.w, g);
}
__device__ __forceinline__ void bfc1(float4& r, float4& i, const G8& g) {
    bfs(r.x, i.x, r.z, i.z, g); bfs(r.y, i.y, r.w, i.w, g);
}
__device__ __forceinline__ void reg_gate0(float4 (&xr)[4], float4 (&xi)[4], const G8& g) {
    bf4v(xr[0],xi[0],xr[1],xi[1],g); bf4v(xr[2],xi[2],xr[3],xi[3],g);
}
__device__ __forceinline__ void reg_gate1(float4 (&xr)[4], float4 (&xi)[4], const G8& g) {
    bf4v(xr[0],xi[0],xr[2],xi[2],g); bf4v(xr[1],xi[1],xr[3],xi[3],g);
}

// ---- lane-partner fetchers ----
__device__ __forceinline__ float p_dpp1(float x) {
    return __uint_as_float((unsigned)__builtin_amdgcn_update_dpp(
        0, (int)__float_as_uint(x), 0xB1, 0xF, 0xF, true));   // quad_perm [1,0,3,2]
}
__device__ __forceinline__ float p_dpp2(float x) {
    return __uint_as_float((unsigned)__builtin_amdgcn_update_dpp(
        0, (int)__float_as_uint(x), 0x4E, 0xF, 0xF, true));   // quad_perm [2,3,0,1]
}
__device__ __forceinline__ float p_x16(float x, int hi) {
#if __has_builtin(__builtin_amdgcn_permlane16_swap)
    u2 r = __builtin_amdgcn_permlane16_swap(__float_as_uint(x), __float_as_uint(x), false, false);
    return __uint_as_float(hi ? r[0] : r[1]);
#else
    (void)hi;
    return __uint_as_float((unsigned)__builtin_amdgcn_ds_swizzle(
        (int)__float_as_uint(x), 0x401F));                    // BitMode xor 16
#endif
}
__device__ __forceinline__ float p_x32(float x, int hi) {
#if __has_builtin(__builtin_amdgcn_permlane32_swap)
    u2 r = __builtin_amdgcn_permlane32_swap(__float_as_uint(x), __float_as_uint(x), false, false);
    return __uint_as_float(hi ? r[0] : r[1]);
#else
    (void)hi;
    return __shfl_xor(x, 32, 64);
#endif
}

// lane-bit gate, per-f4 fused fetch+combine (low register pressure)
#define MAKE_PGATE(NAME, FETCH)                                                     \
__device__ __forceinline__ void NAME(float4 (&xr)[4], float4 (&xi)[4],              \
                                     const G8& g, int bit, int hi) {                \
    float cor = bit ? g.r11 : g.r00, coi = bit ? g.i11 : g.i00;                     \
    float cpr = bit ? g.r10 : g.r01, cpi = bit ? g.i10 : g.i01;                     \
    (void)hi;                                                                       \
    _Pragma("unroll")                                                               \
    for (int i = 0; i < 4; ++i) {                                                   \
        float4 pr, pi, nr, ni;                                                      \
        pr.x = FETCH(xr[i].x); pr.y = FETCH(xr[i].y);                               \
        pr.z = FETCH(xr[i].z); pr.w = FETCH(xr[i].w);                               \
        pi.x = FETCH(xi[i].x); pi.y = FETCH(xi[i].y);                               \
        pi.z = FETCH(xi[i].z); pi.w = FETCH(xi[i].w);                               \
        nr.x = cor*xr[i].x - coi*xi[i].x + cpr*pr.x - cpi*pi.x;                     \
        ni.x = cor*xi[i].x + coi*xr[i].x + cpr*pi.x + cpi*pr.x;                     \
        nr.y = cor*xr[i].y - coi*xi[i].y + cpr*pr.y - cpi*pi.y;                     \
        ni.y = cor*xi[i].y + coi*xr[i].y + cpr*pi.y + cpi*pr.y;                     \
        nr.z = cor*xr[i].z - coi*xi[i].z + cpr*pr.z - cpi*pi.z;                     \
        ni.z = cor*xi[i].z + coi*xr[i].z + cpr*pi.z + cpi*pr.z;                     \
        nr.w = cor*xr[i].w - coi*xi[i].w + cpr*pr.w - cpi*pi.w;                     \
        ni.w = cor*xi[i].w + coi*xr[i].w + cpr*pi.w + cpi*pr.w;                     \
        xr[i] = nr; xi[i] = ni;                                                     \
    }                                                                               \
}
#define F_DPP1(v) p_dpp1(v)
#define F_DPP2(v) p_dpp2(v)
#define F_X16(v)  p_x16(v, hi)
#define F_X32(v)  p_x32(v, hi)
MAKE_PGATE(gate_dpp1, F_DPP1)
MAKE_PGATE(gate_dpp2, F_DPP2)
MAKE_PGATE(gate_x16,  F_X16)
MAKE_PGATE(gate_x32,  F_X32)

__device__ __forceinline__ int pxor12(int x) { x^=x>>1; x^=x>>2; x^=x>>4; x^=x>>8; return x & 0xFFF; }
__device__ __forceinline__ int pxor9(int x)  { x^=x>>1; x^=x>>2; x^=x>>4; x^=x>>8; return x & 0x1FF; }

// ================= pass_high phases (R5 mappings verbatim) =================
__device__ __forceinline__ void highA(float4 (&xr)[4], float4 (&xi)[4],
                                      const G8& my, int h16, int h32) {
    { G8 g = gread(my,22);
#pragma unroll
      for (int j = 0; j < 4; ++j) bfc0(xr[j], xi[j], g); }
    { G8 g = gread(my,21);
#pragma unroll
      for (int j = 0; j < 4; ++j) bfc1(xr[j], xi[j], g); }
    { G8 g = gread(my,5); reg_gate0(xr, xi, g); }
    { G8 g = gread(my,4); reg_gate1(xr, xi, g); }
    { G8 g = gread(my,7); gate_x16(xr, xi, g, h16, h16); }
    { G8 g = gread(my,6); gate_x32(xr, xi, g, h32, h32); }
}
__device__ __forceinline__ void wr_high(char* L, int l, int w,
                                        const float4 (&xr)[4], const float4 (&xi)[4]) {
    const int wslot = ((w << 8) | l) << 4;
#pragma unroll
    for (int j = 0; j < 4; ++j) {
        int a = wslot | (j << 10);
        *(float4*)(L + a) = xr[j];
        *(float4*)(L + a + 65536) = xi[j];
    }
}
__device__ __forceinline__ void rd_high(const char* L, int l, int w,
                                        float4 (&xr)[4], float4 (&xi)[4]) {
    const int sbase = (((l >> 1) & 7) | ((w & 3) << 4) | (((w >> 2) & 3) << 6)
                    | (((l >> 4) & 3) << 9) | ((l & 1) << 11)) << 4;
    constexpr int OFF[4] = {0, 8 << 4, 256 << 4, 264 << 4};
#pragma unroll
    for (int j = 0; j < 4; ++j) {
        int a = sbase | OFF[j];
        xr[j] = *(const float4*)(L + a);
        xi[j] = *(const float4*)(L + a + 65536);
    }
}
__device__ __forceinline__ void highB_store(float4 (&xr)[4], float4 (&xi)[4],
        const G8& my, int l, int w, int blk, int b1, int h16, int h32,
        float4* __restrict__ OR4, float4* __restrict__ OI4) {
    { G8 g = gread(my,8); reg_gate0(xr, xi, g); }
    { G8 g = gread(my,3); reg_gate1(xr, xi, g); }
    { G8 g = gread(my,0); gate_dpp1(xr, xi, g, b1, 0); }
    { G8 g = gread(my,2); gate_x16(xr, xi, g, h16, h16); }
    { G8 g = gread(my,1); gate_x32(xr, xi, g, h32, h32); }
    const int row_base = ((w & 15) << 1) | (((l >> 4) & 3) << 6) | ((l & 1) << 8);
    const int sg = pxor9(row_base);
    const size_t ob = ((size_t)blk << 3) | (size_t)((l >> 1) & 7);
    constexpr int SJ[4] = {0, 0x01, 0x3F, 0x3E};
#pragma unroll
    for (int j = 0; j < 4; ++j) {
        size_t F = (((size_t)(sg ^ SJ[j])) << 12) | ob;
        OR4[F] = xr[j]; OI4[F] = xi[j];
    }
}

__global__ __launch_bounds__(1024, 4)
void pass_high(const float* __restrict__ in_re, const float* __restrict__ in_im,
               const float* __restrict__ param,
               float* __restrict__ out_re, float* __restrict__ out_im) {
    __shared__ __align__(16) char L[131072];
    const int tid = threadIdx.x;
    const int l = tid & 63, w = tid >> 6;
    const int blkA = blockIdx.x, blkB = blockIdx.x + 256;

    const float4* R4p = (const float4*)in_re;
    const float4* I4p = (const float4*)in_im;
    float4 ar[4], ai[4], br_[4], bi_[4];
    const int rb = (l >> 3) | (w << 5);
    const size_t gA = ((size_t)blkA << 3) | (size_t)(l & 7);
    const size_t gB = ((size_t)blkB << 3) | (size_t)(l & 7);
#pragma unroll
    for (int j = 0; j < 4; ++j) {
        size_t gi = (((size_t)(rb | (j << 3))) << 12) | gA;
        ar[j] = R4p[gi]; ai[j] = I4p[gi];
    }
#pragma unroll
    for (int j = 0; j < 4; ++j) {
        size_t gi = (((size_t)(rb | (j << 3))) << 12) | gB;
        br_[j] = R4p[gi]; bi_[j] = I4p[gi];
    }
    G8 my = u3_lane(param, l < 23 ? l : 22);   // trig overlaps loads
    const int b1  = l & 1;
    const int h16 = (l >> 4) & 1, h32 = (l >> 5) & 1;
    float4* OR4 = (float4*)out_re;
    float4* OI4 = (float4*)out_im;

    // Tile A
    highA(ar, ai, my, h16, h32);
    wr_high(L, l, w, ar, ai);                  // LDS virgin: no pre-sync
    __syncthreads();
    rd_high(L, l, w, ar, ai);
    highB_store(ar, ai, my, l, w, blkA, b1, h16, h32, OR4, OI4);  // stores async
    // Tile B epoch A overlaps tile A store drain
    highA(br_, bi_, my, h16, h32);
    __syncthreads();                           // all A RT-reads complete
    wr_high(L, l, w, br_, bi_);
    __syncthreads();
    rd_high(L, l, w, br_, bi_);
    highB_store(br_, bi_, my, l, w, blkB, b1, h16, h32, OR4, OI4);
}

// ================= pass_low phases (R5 mappings verbatim) =================
__device__ __forceinline__ void lowA(float4 (&xr)[4], float4 (&xi)[4],
                                     const G8& my, int b1, int b2, int h16, int h32) {
    { G8 g = gread(my,20); gate_dpp1(xr, xi, g, b1, 0); }
    { G8 g = gread(my,19); gate_dpp2(xr, xi, g, b2, 0); }
    { G8 g = gread(my,16); gate_x16(xr, xi, g, h16, h16); }
    { G8 g = gread(my,15); gate_x32(xr, xi, g, h32, h32); }
    { G8 g = gread(my,14); reg_gate0(xr, xi, g); }
    { G8 g = gread(my,13); reg_gate1(xr, xi, g); }
}
__device__ __forceinline__ void wr_low(char* L, int l, int w,
                                       const float4 (&xr)[4], const float4 (&xi)[4]) {
    const int sw0 = (w << 8) | l;
#pragma unroll
    for (int j = 0; j < 4; ++j) {
        int a = (sw0 | (j << 6)) << 4;
        *(float4*)(L + a) = xr[j];
        *(float4*)(L + a + 65536) = xi[j];
    }
}
__device__ __forceinline__ void rd_low(const char* L, int l, int w,
                                       float4 (&xr)[4], float4 (&xi)[4]) {
    const int sbase = ((l >> 2) & 3) | ((l & 3) << 2) | ((w & 15) << 4)
                    | (((l >> 4) & 3) << 10);
#pragma unroll
    for (int j = 0; j < 4; ++j) {
        int a = (sbase | (j << 8)) << 4;
        xr[j] = *(const float4*)(L + a);
        xi[j] = *(const float4*)(L + a + 65536);
    }
}
__device__ __forceinline__ void lowB_store(float4 (&xr)[4], float4 (&xi)[4],
        const G8& my, int l, int w, int c, int b1, int b2, int h16, int h32,
        float4* __restrict__ R4p, float4* __restrict__ I4p) {
    { G8 g = gread(my,18); gate_dpp1(xr, xi, g, b1, 0); }
    { G8 g = gread(my,17); gate_dpp2(xr, xi, g, b2, 0); }
    { G8 g = gread(my,12); reg_gate0(xr, xi, g); }
    { G8 g = gread(my,11); reg_gate1(xr, xi, g); }
    { G8 g = gread(my,10); gate_x16(xr, xi, g, h16, h16); }
    { G8 g = gread(my, 9); gate_x32(xr, xi, g, h32, h32); }
    const int sbase = ((l >> 2) & 3) | ((l & 3) << 2) | ((w & 15) << 4)
                    | (((l >> 4) & 3) << 10);
    const size_t cb = ((size_t)c) << 12;
    const int px0 = pxor12(sbase);
    const int codd = c & 1;
    const int A12 = codd ? 0xFFF : 0;
    constexpr int PM[4] = {0, 0x1FF, 0x3FF, 0x200};
#pragma unroll
    for (int j = 0; j < 4; ++j) {
        int pxj = px0 ^ PM[j];
        int of4 = pxj ^ A12;
        int b = (pxj ^ codd) & 1;
        float s0r = xr[j].x, s1r = xr[j].y, s2r = xr[j].w, s3r = xr[j].z;
        float s0i = xi[j].x, s1i = xi[j].y, s2i = xi[j].w, s3i = xi[j].z;
        float o0r = b ? s3r : s0r, o1r = b ? s2r : s1r, o2r = b ? s1r : s2r, o3r = b ? s0r : s3r;
        float o0i = b ? s3i : s0i, o1i = b ? s2i : s1i, o2i = b ? s1i : s2i, o3i = b ? s0i : s3i;
        size_t oo = cb | (size_t)of4;
        R4p[oo] = make_float4(o0r, o1r, o2r, o3r);
        I4p[oo] = make_float4(o0i, o1i, o2i, o3i);
    }
}

__global__ __launch_bounds__(1024, 4)
void pass_low(float* __restrict__ sre, float* __restrict__ sim,
              const float* __restrict__ param) {
    __shared__ __align__(16) char L[131072];
    const int tid = threadIdx.x;
    const int l = tid & 63, w = tid >> 6;
    const int cA = blockIdx.x, cB = blockIdx.x + 256;

    float4* R4p = (float4*)sre;
    float4* I4p = (float4*)sim;
    float4 ar[4], ai[4], br_[4], bi_[4];
    const int sw0 = (w << 8) | l;
    const size_t cbA = ((size_t)cA) << 12;
    const size_t cbB = ((size_t)cB) << 12;
#pragma unroll
    for (int j = 0; j < 4; ++j) {
        size_t fi = cbA + (size_t)(sw0 | (j << 6));
        ar[j] = R4p[fi]; ai[j] = I4p[fi];
    }
#pragma unroll
    for (int j = 0; j < 4; ++j) {
        size_t fi = cbB + (size_t)(sw0 | (j << 6));
        br_[j] = R4p[fi]; bi_[j] = I4p[fi];
    }
    G8 my = u3_lane(param, l < 23 ? l : 22);
    const int b1 = l & 1, b2 = (l >> 1) & 1;
    const int h16 = (l >> 4) & 1, h32 = (l >> 5) & 1;

    // Tile A
    lowA(ar, ai, my, b1, b2, h16, h32);
    wr_low(L, l, w, ar, ai);                   // LDS virgin: no pre-sync
    __syncthreads();
    rd_low(L, l, w, ar, ai);
    lowB_store(ar, ai, my, l, w, cA, b1, b2, h16, h32, R4p, I4p);  // stores async
    // Tile B epoch A overlaps tile A store drain
    lowA(br_, bi_, my, b1, b2, h16, h32);
    __syncthreads();                           // all A RT-reads complete
    wr_low(L, l, w, br_, bi_);
    __syncthreads();
    rd_low(L, l, w, br_, bi_);
    lowB_store(br_, bi_, my, l, w, cB, b1, b2, h16, h32, R4p, I4p);
}

extern "C" void kernel_launch(void* const* d_in, const int* in_sizes, int n_in,
                              void* d_out, int out_size, void* d_ws, size_t ws_size,
                              hipStream_t stream) {
    (void)in_sizes; (void)n_in; (void)d_ws; (void)ws_size; (void)out_size;
    const float* in_re = (const float*)d_in[0];
    const float* in_im = (const float*)d_in[1];
    const float* param = (const float*)d_in[2];
    float* out_re = (float*)d_out;
    float* out_im = (float*)d_out + NTOT;

    pass_high<<<256, 1024, 0, stream>>>(in_re, in_im, param, out_re, out_im);
    pass_low <<<256, 1024, 0, stream>>>(out_re, out_im, param);
}